// Round 9
// baseline (579.064 us; speedup 1.0000x reference)
//
#include <hip/hip_runtime.h>
#include <hip/hip_bf16.h>

// Flash attention fwd, causal + key-padding mask, bf16 MFMA, fp32 softmax.
// BH=256, T=1024, D=128, B=32 (mask row = bh % 32). MASK_NUM kept finite so
// degenerate all-masked rows reproduce the reference's uniform softmax over
// ALL 1024 keys (future tiles swept V-only at the end).
//
// Round-9: remove Plds entirely. V key-columns are PERMUTED at staging
// (c(K) chosen so contraction slot k holds the key the PV A-fragment needs),
// letting each lane feed PV directly from its own p[] registers. LDS drops
// 58.9->39.9 KB => 4 blocks/CU (32 waves, occupancy cap 100%).

typedef __attribute__((ext_vector_type(8))) __bf16 bf16x8;
typedef __attribute__((ext_vector_type(8))) short s16x8;
typedef __attribute__((ext_vector_type(4))) short s16x4;
typedef __attribute__((ext_vector_type(2))) short s16x2;
typedef __attribute__((ext_vector_type(4))) float f32x4;

#define T_SEQ    1024
#define D_HEAD   128
#define N_BATCH  32
#define QBLK     128
#define KVBLK    64
#define NWAVES   8
#define NTHR     512
#define NKT      (T_SEQ / KVBLK)   // 16
#define KPAD     136
#define VPAD     72
#define MASK_NUM (-4294967295.0f)  // -2^32+1 -> rounds to -2^32 in fp32 (same as jax)
#define SCALE    0.08838834764831845f

__device__ __forceinline__ short f2bf(float f) {
    union { float f; unsigned u; } v; v.f = f;
    unsigned r = v.u + 0x7fffu + ((v.u >> 16) & 1u);   // RNE
    return (short)(r >> 16);
}

// key -> V lds column, so that column k holds key kappa(k) = the key that
// PV contraction slot k expects when A comes straight from p[] registers:
// kappa(lhi*8+j) = (j>>2)*16 + lhi*4 + (j&3)  (+32 for the second half).
__device__ __forceinline__ int vperm(int K) {
    return (K & 32) | (((K >> 2) & 3) << 3) | (((K >> 4) & 1) << 2) | (K & 3);
}

__global__ __launch_bounds__(NTHR) void fa_kernel(
    const float* __restrict__ Qg, const float* __restrict__ Kg,
    const float* __restrict__ Vg, const int* __restrict__ Mg,
    float* __restrict__ Og)
{
    __shared__ short Klds[KVBLK][KPAD];        // [key][d]
    __shared__ short Vlds[D_HEAD][VPAD];       // transposed+permuted: [d][col]
    __shared__ float Mlds[T_SEQ];              // mask[key] * MASK_NUM (additive)
    __shared__ int   degAny;

    const int bh  = blockIdx.x;                // 0..255 -> XCD = bh%8 (balanced)
    const int qs  = 7 - blockIdx.y;            // heavy q super-tiles dispatch first
    const int tid = threadIdx.x;
    const int w    = tid >> 6;                 // wave 0..7
    const int lane = tid & 63;
    const int l16  = lane & 15;
    const int lhi  = lane >> 4;                // 0..3

    const int    bidx   = bh & (N_BATCH - 1);
    const size_t base   = (size_t)bh * T_SEQ * D_HEAD;
    const int    qrow0  = qs * QBLK + w * 16;  // wave's first q row
    const int    qrow   = qrow0 + l16;         // THIS lane's q row (softmax row)
    const int    kt_max = 2 * qs + 1;

    // V staging geometry: d = tid&127 (lane-consecutive), key-pair kp.
    const int vd  = tid & 127;
    const int vkp = tid >> 7;                  // 0..3 base; +4 per u

    if (tid == 0) degAny = 0;
    // ---- mask table: additive float per key (visible after first barrier) ----
    Mlds[tid]        = (float)Mg[bidx * T_SEQ + tid] * MASK_NUM;
    Mlds[tid + NTHR] = (float)Mg[bidx * T_SEQ + tid + NTHR] * MASK_NUM;

    // ---- Q fragments (B-operand): col=l16=q, k(d)=dk*32+lhi*8+j ----
    s16x8 qf[4];
    {
        const float* qp = Qg + base + (size_t)qrow * D_HEAD + lhi * 8;
        #pragma unroll
        for (int dk = 0; dk < 4; ++dk) {
            float4 a = *(const float4*)(qp + dk * 32);
            float4 c = *(const float4*)(qp + dk * 32 + 4);
            s16x8 t;
            t[0] = f2bf(a.x); t[1] = f2bf(a.y); t[2] = f2bf(a.z); t[3] = f2bf(a.w);
            t[4] = f2bf(c.x); t[5] = f2bf(c.y); t[6] = f2bf(c.z); t[7] = f2bf(c.w);
            qf[dk] = t;
        }
    }

    f32x4 acc[8];                              // O: col=l16=d, row=lhi*4+r=q'
    #pragma unroll
    for (int i = 0; i < 8; ++i) acc[i] = (f32x4){0.f, 0.f, 0.f, 0.f};
    float m_run = -INFINITY, l_run = 0.f;      // per-lane: one q-row (q = qrow)

    // ---- register prefetch of tile 0 ----
    float4 kpre[4];
    float  vpre0[8], vpre1[8];
    {
        const float4* kg4 = (const float4*)(Kg + base);
        const float*  vg  = Vg + base;
        #pragma unroll
        for (int u = 0; u < 4; ++u)
            kpre[u] = kg4[tid + NTHR * u];
        #pragma unroll
        for (int u = 0; u < 8; ++u) {
            int kp = vkp + 4 * u;
            vpre0[u] = vg[(size_t)(2 * kp) * D_HEAD + vd];
            vpre1[u] = vg[(size_t)(2 * kp + 1) * D_HEAD + vd];
        }
    }

    for (int kt = 0; kt <= kt_max; ++kt) {
        const int kvbase = kt * KVBLK;

        // ---- convert prefetched regs -> LDS ----
        #pragma unroll
        for (int u = 0; u < 4; ++u) {
            int id  = tid + NTHR * u;
            int row = id >> 5;
            int c4  = id & 31;
            s16x4 s4;
            s4[0] = f2bf(kpre[u].x); s4[1] = f2bf(kpre[u].y);
            s4[2] = f2bf(kpre[u].z); s4[3] = f2bf(kpre[u].w);
            *(s16x4*)&Klds[row][c4 * 4] = s4;
        }
        #pragma unroll
        for (int u = 0; u < 8; ++u) {
            int kp  = vkp + 4 * u;
            int col = vperm(2 * kp);           // c(2kp+1) = c(2kp)+1
            s16x2 s2; s2[0] = f2bf(vpre0[u]); s2[1] = f2bf(vpre1[u]);
            *(s16x2*)&Vlds[vd][col] = s2;
        }
        __syncthreads();   // stage + mask table visible

        // ---- issue NEXT tile's loads; consumed after compute+barrier ----
        if (kt < kt_max) {
            const float4* kg4 = (const float4*)(Kg + base + (size_t)(kvbase + KVBLK) * D_HEAD);
            const float*  vg  = Vg + base + (size_t)(kvbase + KVBLK) * D_HEAD;
            #pragma unroll
            for (int u = 0; u < 4; ++u)
                kpre[u] = kg4[tid + NTHR * u];
            #pragma unroll
            for (int u = 0; u < 8; ++u) {
                int kp = vkp + 4 * u;
                vpre0[u] = vg[(size_t)(2 * kp) * D_HEAD + vd];
                vpre1[u] = vg[(size_t)(2 * kp + 1) * D_HEAD + vd];
            }
        }

        // ---- QK^T swapped: S^T = K * Q^T; col=l16=q, row=k ----
        f32x4 sc[4];
        #pragma unroll
        for (int cf = 0; cf < 4; ++cf) sc[cf] = (f32x4){0.f, 0.f, 0.f, 0.f};
        __builtin_amdgcn_s_setprio(1);
        #pragma unroll
        for (int cf = 0; cf < 4; ++cf) {
            #pragma unroll
            for (int dk = 0; dk < 4; ++dk) {
                bf16x8 kf = *(bf16x8*)&Klds[cf * 16 + l16][dk * 32 + lhi * 8];
                sc[cf] = __builtin_amdgcn_mfma_f32_16x16x32_bf16(
                    kf, __builtin_bit_cast(bf16x8, qf[dk]), sc[cf], 0, 0, 0);
            }
        }
        __builtin_amdgcn_s_setprio(0);

        // ---- mask + scale + causal; lane's key = kvbase + cf*16 + lhi*4 + r ----
        float p[4][4];
        const bool diag = (kvbase + KVBLK - 1 > qrow0);
        #pragma unroll
        for (int cf = 0; cf < 4; ++cf) {
            float4 mv = *(const float4*)&Mlds[kvbase + cf * 16 + lhi * 4];
            #pragma unroll
            for (int r = 0; r < 4; ++r) {
                float s = sc[cf][r] * SCALE + ((const float*)&mv)[r];
                int key = kvbase + cf * 16 + lhi * 4 + r;
                if (diag && key > qrow) s = MASK_NUM;
                p[cf][r] = s;
            }
        }

        // ---- online softmax: in-lane tree + 2 shuffles (4 lanes share a q-row) ----
        float mx0 = fmaxf(fmaxf(p[0][0], p[0][1]), fmaxf(p[0][2], p[0][3]));
        float mx1 = fmaxf(fmaxf(p[1][0], p[1][1]), fmaxf(p[1][2], p[1][3]));
        float mx2 = fmaxf(fmaxf(p[2][0], p[2][1]), fmaxf(p[2][2], p[2][3]));
        float mx3 = fmaxf(fmaxf(p[3][0], p[3][1]), fmaxf(p[3][2], p[3][3]));
        float mx  = fmaxf(fmaxf(mx0, mx1), fmaxf(mx2, mx3));
        mx = fmaxf(mx, __shfl_xor(mx, 16));
        mx = fmaxf(mx, __shfl_xor(mx, 32));
        float mnew  = fmaxf(m_run, mx);
        float alpha = __expf(m_run - mnew);    // exp(-inf)=0 first time
        m_run = mnew;
        float rs = 0.f;
        #pragma unroll
        for (int cf = 0; cf < 4; ++cf)
            #pragma unroll
            for (int r = 0; r < 4; ++r) {
                float pv = __expf(p[cf][r] - mnew);
                p[cf][r] = pv;
                rs += pv;
            }
        rs += __shfl_xor(rs, 16);
        rs += __shfl_xor(rs, 32);
        l_run = l_run * alpha + rs;

        // ---- rescale acc: alpha for q'=lhi*4+r lives in lane l16=q' ----
        float a0 = __shfl(alpha, lhi * 4 + 0);
        float a1 = __shfl(alpha, lhi * 4 + 1);
        float a2 = __shfl(alpha, lhi * 4 + 2);
        float a3 = __shfl(alpha, lhi * 4 + 3);
        #pragma unroll
        for (int cfo = 0; cfo < 8; ++cfo) {
            acc[cfo][0] *= a0; acc[cfo][1] *= a1;
            acc[cfo][2] *= a2; acc[cfo][3] *= a3;
        }

        // ---- P -> A-fragments DIRECTLY from registers (V columns permuted) ----
        s16x8 pa0, pa1;
        #pragma unroll
        for (int r = 0; r < 4; ++r) {
            pa0[r]     = f2bf(p[0][r]);
            pa0[r + 4] = f2bf(p[1][r]);
            pa1[r]     = f2bf(p[2][r]);
            pa1[r + 4] = f2bf(p[3][r]);
        }

        // ---- PV: O[16q x 128d] += P[16q x 64k] * V[64k x 128d] ----
        __builtin_amdgcn_s_setprio(1);
        #pragma unroll
        for (int cfo = 0; cfo < 8; ++cfo) {
            bf16x8 vf0 = *(bf16x8*)&Vlds[cfo * 16 + l16][lhi * 8];
            bf16x8 vf1 = *(bf16x8*)&Vlds[cfo * 16 + l16][32 + lhi * 8];
            acc[cfo] = __builtin_amdgcn_mfma_f32_16x16x32_bf16(
                __builtin_bit_cast(bf16x8, pa0), vf0, acc[cfo], 0, 0, 0);
            acc[cfo] = __builtin_amdgcn_mfma_f32_16x16x32_bf16(
                __builtin_bit_cast(bf16x8, pa1), vf1, acc[cfo], 0, 0, 0);
        }
        __builtin_amdgcn_s_setprio(0);
        __syncthreads();   // all reads done before next stage overwrites
    }

    // ---- degenerate rows: whole causal prefix masked => reference weights
    // ALL 1024 keys uniformly. Sweep future tiles V-only; A-frag row is the
    // lane's own q-row, so P is a splat of the lane's own pv (1 deg, 0 else).
    {
        const bool deg = (m_run < -1e9f);
        if (deg) degAny = 1;
        __syncthreads();
        if (degAny) {
            const float pv = deg ? 1.0f : 0.0f;
            const short pb = f2bf(pv);
            s16x8 pa;
            #pragma unroll
            for (int j = 0; j < 8; ++j) pa[j] = pb;
            for (int kt = kt_max + 1; kt < NKT; ++kt) {
                const float* vg = Vg + base + (size_t)(kt * KVBLK) * D_HEAD;
                #pragma unroll
                for (int u = 0; u < 8; ++u) {
                    int kp  = vkp + 4 * u;
                    int col = vperm(2 * kp);
                    float v0 = vg[(size_t)(2 * kp) * D_HEAD + vd];
                    float v1 = vg[(size_t)(2 * kp + 1) * D_HEAD + vd];
                    s16x2 s2; s2[0] = f2bf(v0); s2[1] = f2bf(v1);
                    *(s16x2*)&Vlds[vd][col] = s2;
                }
                __syncthreads();
                l_run += 64.0f * pv;
                #pragma unroll
                for (int cfo = 0; cfo < 8; ++cfo) {
                    bf16x8 vf0 = *(bf16x8*)&Vlds[cfo * 16 + l16][lhi * 8];
                    bf16x8 vf1 = *(bf16x8*)&Vlds[cfo * 16 + l16][32 + lhi * 8];
                    acc[cfo] = __builtin_amdgcn_mfma_f32_16x16x32_bf16(
                        __builtin_bit_cast(bf16x8, pa), vf0, acc[cfo], 0, 0, 0);
                    acc[cfo] = __builtin_amdgcn_mfma_f32_16x16x32_bf16(
                        __builtin_bit_cast(bf16x8, pa), vf1, acc[cfo], 0, 0, 0);
                }
                __syncthreads();
            }
        }
    }

    // ---- epilogue: O = acc / l; 1/l for q'=lhi*4+r from lane l16=q' ----
    float invl = 1.0f / l_run;
    float i0 = __shfl(invl, lhi * 4 + 0);
    float i1 = __shfl(invl, lhi * 4 + 1);
    float i2 = __shfl(invl, lhi * 4 + 2);
    float i3 = __shfl(invl, lhi * 4 + 3);
    float* op = Og + base;
    #pragma unroll
    for (int cfo = 0; cfo < 8; ++cfo) {
        op[(size_t)(qrow0 + lhi * 4 + 0) * D_HEAD + cfo * 16 + l16] = acc[cfo][0] * i0;
        op[(size_t)(qrow0 + lhi * 4 + 1) * D_HEAD + cfo * 16 + l16] = acc[cfo][1] * i1;
        op[(size_t)(qrow0 + lhi * 4 + 2) * D_HEAD + cfo * 16 + l16] = acc[cfo][2] * i2;
        op[(size_t)(qrow0 + lhi * 4 + 3) * D_HEAD + cfo * 16 + l16] = acc[cfo][3] * i3;
    }
}

extern "C" void kernel_launch(void* const* d_in, const int* in_sizes, int n_in,
                              void* d_out, int out_size, void* d_ws, size_t ws_size,
                              hipStream_t stream) {
    const float* Q = (const float*)d_in[0];
    const float* K = (const float*)d_in[1];
    const float* V = (const float*)d_in[2];
    const int*   M = (const int*)d_in[3];
    float*       O = (float*)d_out;
    // x = bh (XCD = bh%8, balanced), y: qs = 7-y (heavy blocks dispatch first)
    dim3 grid(256, T_SEQ / QBLK);
    fa_kernel<<<grid, dim3(NTHR), 0, stream>>>(Q, K, V, M, O);
}